// Round 3
// baseline (1412.994 us; speedup 1.0000x reference)
//
#include <hip/hip_runtime.h>

#define NCOLS 8
#define BLOCK 256
#define NB    512           // streaming blocks for hist/scatter
#define CPAD  16            // u32 stride for line-padded counters (64 B)

// ---------- index-width autodetect (int32 vs int64 COO indices) ----------
// All index values < 2^20, so int64 data has zero high words. P(false pos) ~ 1e-96.
__device__ __forceinline__ int detect_is64(const void* p, int* s_flag) {
    if (threadIdx.x == 0) {
        const unsigned* w = (const unsigned*)p;
        int is64 = 1;
        #pragma unroll
        for (int k = 0; k < 16; ++k) is64 &= (w[2 * k + 1] == 0u) ? 1 : 0;
        *s_flag = is64;
    }
    __syncthreads();
    return *s_flag;
}

__device__ __forceinline__ int load_idx(const void* p, int i, int is64) {
    return is64 ? (int)((const long long*)p)[i] : ((const int*)p)[i];
}

// ---------- zero the padded bucket counts ----------
__global__ __launch_bounds__(BLOCK) void k_zero_counts(unsigned* __restrict__ counts, int nwords) {
    int i = blockIdx.x * BLOCK + threadIdx.x;
    if (i < nwords) counts[i] = 0u;
}

// ---------- per-block histogram of row buckets ----------
template<int NBKT, int LG2RPB>
__global__ __launch_bounds__(BLOCK) void k_hist(
    const void* __restrict__ rowp, int nnz, int chunk,
    unsigned* __restrict__ counts, unsigned* __restrict__ blockhist)
{
    __shared__ unsigned h[NBKT];
    __shared__ int s_flag;
    const int is64 = detect_is64(rowp, &s_flag);
    for (int b = threadIdx.x; b < NBKT; b += BLOCK) h[b] = 0u;
    __syncthreads();

    const int beg = blockIdx.x * chunk;
    const int end = min(nnz, beg + chunk);
    for (int i = beg + threadIdx.x; i < end; i += BLOCK) {
        int r = load_idx(rowp, i, is64);
        atomicAdd(&h[r >> LG2RPB], 1u);
    }
    __syncthreads();
    for (int b = threadIdx.x; b < NBKT; b += BLOCK) {
        unsigned c = h[b];
        blockhist[(size_t)blockIdx.x * NBKT + b] = c;
        if (c) atomicAdd(&counts[(size_t)b * CPAD], c);
    }
}

// ---------- exclusive scan over bucket counts (1 block, 1024 threads) ----------
// Counts are padded up to a multiple of 4 records so bucket bases are
// 32 B aligned (enables uint4 record loads in k_accum).
template<int NBKT>
__global__ __launch_bounds__(1024) void k_scan(
    const unsigned* __restrict__ counts,
    unsigned* __restrict__ base, unsigned* __restrict__ cursor)
{
    __shared__ unsigned s[1024];
    const int t = threadIdx.x;
    constexpr int E = NBKT / 1024;
    unsigned c[E];
    unsigned sum = 0;
    #pragma unroll
    for (int e = 0; e < E; ++e) {
        c[e] = (counts[(size_t)(t * E + e) * CPAD] + 3u) & ~3u;
        sum += c[e];
    }
    s[t] = sum;
    __syncthreads();
    for (int off = 1; off < 1024; off <<= 1) {
        unsigned v = (t >= off) ? s[t - off] : 0u;
        __syncthreads();
        s[t] += v;
        __syncthreads();
    }
    unsigned excl = s[t] - sum;
    #pragma unroll
    for (int e = 0; e < E; ++e) {
        base[t * E + e] = excl;
        cursor[(size_t)(t * E + e) * CPAD] = excl;
        excl += c[e];
    }
    if (t == 1023) base[NBKT] = s[t];
}

// ---------- scatter records into bucket-sorted order ----------
// record = (localrow<<20 | col, bits(val)), 8 bytes
template<int NBKT, int LG2RPB>
__global__ __launch_bounds__(BLOCK) void k_scatter(
    const float* __restrict__ vals, const void* __restrict__ rowp,
    const void* __restrict__ colp, int nnz, int chunk,
    const unsigned* __restrict__ blockhist, unsigned* __restrict__ cursor,
    uint2* __restrict__ records)
{
    __shared__ unsigned lcur[NBKT];
    __shared__ int s_flag;
    const int is64 = detect_is64(rowp, &s_flag);

    for (int b = threadIdx.x; b < NBKT; b += BLOCK) {
        unsigned h = blockhist[(size_t)blockIdx.x * NBKT + b];
        lcur[b] = h ? atomicAdd(&cursor[(size_t)b * CPAD], h) : 0u;
    }
    __syncthreads();

    const int beg = blockIdx.x * chunk;
    const int end = min(nnz, beg + chunk);
    constexpr unsigned RM = (1u << LG2RPB) - 1u;
    for (int i = beg + threadIdx.x; i < end; i += BLOCK) {
        int r = load_idx(rowp, i, is64);
        int c = load_idx(colp, i, is64);
        float v = vals[i];
        unsigned pos = atomicAdd(&lcur[r >> LG2RPB], 1u);
        records[pos] = make_uint2((((unsigned)r & RM) << 20) | (unsigned)c,
                                  __float_as_uint(v));
    }
}

// ---------- per-bucket gather + LDS accumulate + coalesced store ----------
template<int RPB>
__global__ __launch_bounds__(BLOCK, 6) void k_accum(
    const uint2* __restrict__ records, const unsigned* __restrict__ base,
    const unsigned* __restrict__ cursor,
    const float* __restrict__ field, float* __restrict__ out, int n)
{
    __shared__ float acc[NCOLS * RPB];
    for (int i = threadIdx.x; i < NCOLS * RPB; i += BLOCK) acc[i] = 0.f;
    __syncthreads();

    const int b = blockIdx.x;
    const unsigned beg = base[b];                         // 4-record aligned
    const unsigned end = cursor[(size_t)b * CPAD];        // beg + actual count
    const unsigned cnt = end - beg;
    const unsigned nq  = cnt >> 2;

    // main loop: 4 records per thread per iteration (2x uint4 loads, 4 gathers in flight)
    for (unsigned q = threadIdx.x; q < nq; q += BLOCK) {
        const unsigned i = beg + (q << 2);
        const uint4 ra = *(const uint4*)(records + i);
        const uint4 rb = *(const uint4*)(records + i + 2);

        const unsigned k0 = ra.x, k1 = ra.z, k2 = rb.x, k3 = rb.z;
        const float v0 = __uint_as_float(ra.y);
        const float v1 = __uint_as_float(ra.w);
        const float v2 = __uint_as_float(rb.y);
        const float v3 = __uint_as_float(rb.w);

        const float4* p0 = (const float4*)(field + (size_t)(k0 & 0xFFFFFu) * NCOLS);
        const float4* p1 = (const float4*)(field + (size_t)(k1 & 0xFFFFFu) * NCOLS);
        const float4* p2 = (const float4*)(field + (size_t)(k2 & 0xFFFFFu) * NCOLS);
        const float4* p3 = (const float4*)(field + (size_t)(k3 & 0xFFFFFu) * NCOLS);
        // issue all gathers before consuming any
        const float4 a0 = p0[0], b0 = p0[1];
        const float4 a1 = p1[0], b1 = p1[1];
        const float4 a2 = p2[0], b2 = p2[1];
        const float4 a3 = p3[0], b3 = p3[1];

        const unsigned l0 = k0 >> 20, l1 = k1 >> 20, l2 = k2 >> 20, l3 = k3 >> 20;

        atomicAdd(&acc[0 * RPB + l0], v0 * a0.x);
        atomicAdd(&acc[1 * RPB + l0], v0 * a0.y);
        atomicAdd(&acc[2 * RPB + l0], v0 * a0.z);
        atomicAdd(&acc[3 * RPB + l0], v0 * a0.w);
        atomicAdd(&acc[4 * RPB + l0], v0 * b0.x);
        atomicAdd(&acc[5 * RPB + l0], v0 * b0.y);
        atomicAdd(&acc[6 * RPB + l0], v0 * b0.z);
        atomicAdd(&acc[7 * RPB + l0], v0 * b0.w);

        atomicAdd(&acc[0 * RPB + l1], v1 * a1.x);
        atomicAdd(&acc[1 * RPB + l1], v1 * a1.y);
        atomicAdd(&acc[2 * RPB + l1], v1 * a1.z);
        atomicAdd(&acc[3 * RPB + l1], v1 * a1.w);
        atomicAdd(&acc[4 * RPB + l1], v1 * b1.x);
        atomicAdd(&acc[5 * RPB + l1], v1 * b1.y);
        atomicAdd(&acc[6 * RPB + l1], v1 * b1.z);
        atomicAdd(&acc[7 * RPB + l1], v1 * b1.w);

        atomicAdd(&acc[0 * RPB + l2], v2 * a2.x);
        atomicAdd(&acc[1 * RPB + l2], v2 * a2.y);
        atomicAdd(&acc[2 * RPB + l2], v2 * a2.z);
        atomicAdd(&acc[3 * RPB + l2], v2 * a2.w);
        atomicAdd(&acc[4 * RPB + l2], v2 * b2.x);
        atomicAdd(&acc[5 * RPB + l2], v2 * b2.y);
        atomicAdd(&acc[6 * RPB + l2], v2 * b2.z);
        atomicAdd(&acc[7 * RPB + l2], v2 * b2.w);

        atomicAdd(&acc[0 * RPB + l3], v3 * a3.x);
        atomicAdd(&acc[1 * RPB + l3], v3 * a3.y);
        atomicAdd(&acc[2 * RPB + l3], v3 * a3.z);
        atomicAdd(&acc[3 * RPB + l3], v3 * a3.w);
        atomicAdd(&acc[4 * RPB + l3], v3 * b3.x);
        atomicAdd(&acc[5 * RPB + l3], v3 * b3.y);
        atomicAdd(&acc[6 * RPB + l3], v3 * b3.z);
        atomicAdd(&acc[7 * RPB + l3], v3 * b3.w);
    }

    // tail (< 4 records)
    {
        const unsigned i = beg + (nq << 2) + threadIdx.x;
        if (i < end) {
            const uint2 rec = records[i];
            const unsigned col = rec.x & 0xFFFFFu;
            const unsigned lr  = rec.x >> 20;
            const float v = __uint_as_float(rec.y);
            const float4* f = (const float4*)(field + (size_t)col * NCOLS);
            const float4 f0 = f[0], f1 = f[1];
            atomicAdd(&acc[0 * RPB + lr], v * f0.x);
            atomicAdd(&acc[1 * RPB + lr], v * f0.y);
            atomicAdd(&acc[2 * RPB + lr], v * f0.z);
            atomicAdd(&acc[3 * RPB + lr], v * f0.w);
            atomicAdd(&acc[4 * RPB + lr], v * f1.x);
            atomicAdd(&acc[5 * RPB + lr], v * f1.y);
            atomicAdd(&acc[6 * RPB + lr], v * f1.z);
            atomicAdd(&acc[7 * RPB + lr], v * f1.w);
        }
    }
    __syncthreads();

    const size_t row0 = (size_t)b * RPB;
    for (int t = threadIdx.x; t < NCOLS * RPB; t += BLOCK) {
        int r = t >> 3, j = t & 7;
        size_t gr = row0 + (size_t)r;
        if (gr < (size_t)n) out[gr * NCOLS + j] = acc[j * RPB + r];
    }
}

// ---------- fallback (round-1 atomic path) if workspace is too small ----------
__global__ __launch_bounds__(BLOCK) void lap_zero_kernel(float4* __restrict__ out, int n4) {
    int i = blockIdx.x * BLOCK + threadIdx.x;
    if (i < n4) out[i] = make_float4(0.f, 0.f, 0.f, 0.f);
}

__global__ __launch_bounds__(BLOCK) void lap_spmm_atomic(
    const float* __restrict__ vals, const void* __restrict__ rowp,
    const void* __restrict__ colp, const float* __restrict__ field,
    float* __restrict__ out, int nnz)
{
    __shared__ int s_flag;
    const int is64 = detect_is64(rowp, &s_flag);
    int i = blockIdx.x * BLOCK + threadIdx.x;
    if (i >= nnz) return;
    float v = vals[i];
    int r = load_idx(rowp, i, is64);
    int c = load_idx(colp, i, is64);
    const float4* f = (const float4*)(field + (size_t)c * NCOLS);
    float4 f0 = f[0], f1 = f[1];
    float* o = out + (size_t)r * NCOLS;
    unsafeAtomicAdd(o + 0, v * f0.x);
    unsafeAtomicAdd(o + 1, v * f0.y);
    unsafeAtomicAdd(o + 2, v * f0.z);
    unsafeAtomicAdd(o + 3, v * f0.w);
    unsafeAtomicAdd(o + 4, v * f1.x);
    unsafeAtomicAdd(o + 5, v * f1.y);
    unsafeAtomicAdd(o + 6, v * f1.z);
    unsafeAtomicAdd(o + 7, v * f1.w);
}

// ---------- host-side config + launch ----------
template<int NBKT, int LG2RPB>
static void run_binned(const float* field, const float* vals, const void* rowp,
                       const void* colp, float* out, int nnz, int n,
                       char* ws, hipStream_t stream)
{
    constexpr int RPB = 1 << LG2RPB;
    const size_t o_counts = 0;
    const size_t o_base   = o_counts + (size_t)NBKT * CPAD * 4;
    const size_t o_cursor = (o_base + (size_t)(NBKT + 1) * 4 + 255) & ~(size_t)255;
    const size_t o_bh     = o_cursor + (size_t)NBKT * CPAD * 4;
    const size_t o_rec    = o_bh + (size_t)NB * NBKT * 4;

    unsigned* counts    = (unsigned*)(ws + o_counts);
    unsigned* base      = (unsigned*)(ws + o_base);
    unsigned* cursor    = (unsigned*)(ws + o_cursor);
    unsigned* blockhist = (unsigned*)(ws + o_bh);
    uint2*    records   = (uint2*)   (ws + o_rec);

    const int chunk = (nnz + NB - 1) / NB;
    const int nwords = NBKT * CPAD;

    k_zero_counts<<<(nwords + BLOCK - 1) / BLOCK, BLOCK, 0, stream>>>(counts, nwords);
    k_hist<NBKT, LG2RPB><<<NB, BLOCK, 0, stream>>>(rowp, nnz, chunk, counts, blockhist);
    k_scan<NBKT><<<1, 1024, 0, stream>>>(counts, base, cursor);
    k_scatter<NBKT, LG2RPB><<<NB, BLOCK, 0, stream>>>(vals, rowp, colp, nnz, chunk,
                                                      blockhist, cursor, records);
    k_accum<RPB><<<NBKT, BLOCK, 0, stream>>>(records, base, cursor, field, out, n);
}

template<int NBKT>
static size_t ws_need(int nnz)
{
    const size_t o_base   = (size_t)NBKT * CPAD * 4;
    const size_t o_cursor = (o_base + (size_t)(NBKT + 1) * 4 + 255) & ~(size_t)255;
    const size_t o_bh     = o_cursor + (size_t)NBKT * CPAD * 4;
    const size_t o_rec    = o_bh + (size_t)NB * NBKT * 4;
    return o_rec + ((size_t)nnz + 4 * NBKT) * 8;
}

extern "C" void kernel_launch(void* const* d_in, const int* in_sizes, int n_in,
                              void* d_out, int out_size, void* d_ws, size_t ws_size,
                              hipStream_t stream) {
    const float* field = (const float*)d_in[0];
    const float* vals  = (const float*)d_in[1];
    const void*  rowp  = d_in[2];
    const void*  colp  = d_in[3];
    float* out = (float*)d_out;

    const int nnz = in_sizes[1];
    const int n   = out_size / NCOLS;
    char* ws = (char*)d_ws;

    if (ws_size >= ws_need<2048>(nnz) && n <= 2048 * 512) {
        run_binned<2048, 9>(field, vals, rowp, colp, out, nnz, n, ws, stream);
        return;
    }
    if (ws_size >= ws_need<1024>(nnz) && n <= 1024 * 1024) {
        run_binned<1024, 10>(field, vals, rowp, colp, out, nnz, n, ws, stream);
        return;
    }

    // fallback: direct atomic scatter
    const int n4 = out_size / 4;
    lap_zero_kernel<<<(n4 + BLOCK - 1) / BLOCK, BLOCK, 0, stream>>>((float4*)out, n4);
    lap_spmm_atomic<<<(nnz + BLOCK - 1) / BLOCK, BLOCK, 0, stream>>>(
        vals, rowp, colp, field, out, nnz);
}

// Round 4
// 1373.765 us; speedup vs baseline: 1.0286x; 1.0286x over previous
//
#include <hip/hip_runtime.h>

#define NCOLS  8
#define BLOCK  256
#define NB     256          // streaming blocks for hist/scatter
#define NBKT   1024         // row buckets (one accum block each)
#define LG2RPB 10
#define RPB    1024         // rows per bucket
#define NCB    32           // col windows per bucket (local sort key)

// ---------- index-width autodetect (int32 vs int64 COO indices) ----------
// All index values < 2^20, so int64 data has zero high words. P(false pos) ~ 1e-96.
// Per-thread (uniform, broadcast loads) — no LDS needed.
__device__ __forceinline__ int detect_is64(const void* p) {
    const unsigned* w = (const unsigned*)p;
    int is64 = 1;
    #pragma unroll
    for (int k = 0; k < 16; ++k) is64 &= (w[2 * k + 1] == 0u) ? 1 : 0;
    return is64;
}

__device__ __forceinline__ int load_idx(const void* p, int i, int is64) {
    return is64 ? (int)((const long long*)p)[i] : ((const int*)p)[i];
}

// ---------- k1: per-block row-bucket histogram (no global atomics) ----------
__global__ __launch_bounds__(BLOCK) void k_hist(
    const void* __restrict__ rowp, int nnz, int chunk, unsigned* __restrict__ hist)
{
    __shared__ unsigned h[NBKT];
    const int is64 = detect_is64(rowp);
    for (int i = threadIdx.x; i < NBKT; i += BLOCK) h[i] = 0u;
    __syncthreads();
    const int beg = blockIdx.x * chunk;
    const int end = min(nnz, beg + chunk);
    for (int i = beg + threadIdx.x; i < end; i += BLOCK)
        atomicAdd(&h[load_idx(rowp, i, is64) >> LG2RPB], 1u);
    __syncthreads();
    unsigned* row = hist + (size_t)blockIdx.x * NBKT;
    for (int i = threadIdx.x; i < NBKT; i += BLOCK) row[i] = h[i];
}

// ---------- k2: cross-block prefix per bucket (transpose walk, no atomics) ----------
__global__ __launch_bounds__(BLOCK) void k_colsum(
    unsigned* __restrict__ hist, unsigned* __restrict__ total)
{
    const int c = blockIdx.x * BLOCK + threadIdx.x;   // bucket id, grid covers NBKT
    if (c >= NBKT) return;
    unsigned run = 0;
    for (int b = 0; b < NB; ++b) {
        unsigned t = hist[(size_t)b * NBKT + c];
        hist[(size_t)b * NBKT + c] = run;             // in-place -> per-block prefix
        run += t;
    }
    total[c] = run;
}

// ---------- k3: exclusive scan over bucket totals (1 block, 1024 threads) ----------
__global__ __launch_bounds__(1024) void k_scan(
    const unsigned* __restrict__ total, unsigned* __restrict__ base)
{
    __shared__ unsigned s[NBKT];
    const int t = threadIdx.x;
    const unsigned c = total[t];
    s[t] = c;
    __syncthreads();
    for (int off = 1; off < NBKT; off <<= 1) {
        unsigned v = (t >= off) ? s[t - off] : 0u;
        __syncthreads();
        s[t] += v;
        __syncthreads();
    }
    base[t] = s[t] - c;
    if (t == NBKT - 1) base[NBKT] = s[t];
}

// ---------- k4: scatter into bucket-grouped order (LDS cursors, no global atomics) ----------
// record = (localrow<<20 | col, bits(val)), 8 bytes
__global__ __launch_bounds__(BLOCK) void k_scatter(
    const float* __restrict__ vals, const void* __restrict__ rowp,
    const void* __restrict__ colp, int nnz, int chunk,
    const unsigned* __restrict__ hist, const unsigned* __restrict__ base,
    uint2* __restrict__ records)
{
    __shared__ unsigned cur[NBKT];
    const int is64 = detect_is64(rowp);
    const unsigned* pref = hist + (size_t)blockIdx.x * NBKT;
    for (int i = threadIdx.x; i < NBKT; i += BLOCK) cur[i] = base[i] + pref[i];
    __syncthreads();
    const int beg = blockIdx.x * chunk;
    const int end = min(nnz, beg + chunk);
    for (int i = beg + threadIdx.x; i < end; i += BLOCK) {
        int r = load_idx(rowp, i, is64);
        int c = load_idx(colp, i, is64);
        float v = vals[i];
        unsigned pos = atomicAdd(&cur[r >> LG2RPB], 1u);
        records[pos] = make_uint2((((unsigned)r & (RPB - 1u)) << 20) | (unsigned)c,
                                  __float_as_uint(v));
    }
}

// ---------- k5: per-bucket local col-sort + windowed gather + LDS accumulate ----------
__global__ __launch_bounds__(BLOCK) void k_accum2(
    const uint2* __restrict__ records, const unsigned* __restrict__ base,
    uint2* __restrict__ scratch2, const float* __restrict__ field,
    float* __restrict__ out, int n, int lg2cpb)
{
    __shared__ float acc[NCOLS * RPB];        // 32 KB, transposed: acc[j*RPB + lr]
    __shared__ unsigned cnt[NCB];
    __shared__ unsigned pref[NCB + 1];
    __shared__ unsigned cur[NCB];

    const int b = blockIdx.x;
    const unsigned beg = base[b], end = base[b + 1];

    for (int i = threadIdx.x; i < NCOLS * RPB; i += BLOCK) acc[i] = 0.f;
    if (threadIdx.x < NCB) cnt[threadIdx.x] = 0u;
    __syncthreads();

    // Phase A: count col-windows
    for (unsigned i = beg + threadIdx.x; i < end; i += BLOCK) {
        unsigned cb = (records[i].x & 0xFFFFFu) >> lg2cpb;
        atomicAdd(&cnt[cb], 1u);
    }
    __syncthreads();
    if (threadIdx.x == 0) {
        unsigned run = beg;
        #pragma unroll
        for (int k = 0; k < NCB; ++k) { pref[k] = run; cur[k] = run; run += cnt[k]; }
        pref[NCB] = run;                      // == end
    }
    __syncthreads();

    // Phase B: local counting-sort by col-window into scratch2
    for (unsigned i = beg + threadIdx.x; i < end; i += BLOCK) {
        uint2 rec = records[i];
        unsigned cb = (rec.x & 0xFFFFFu) >> lg2cpb;
        unsigned pos = atomicAdd(&cur[cb], 1u);
        scratch2[pos] = rec;
    }
    __threadfence_block();
    __syncthreads();

    // Phase C: window-by-window gather (field slice stays L2-hot) + LDS fp atomics
    for (int k = 0; k < NCB; ++k) {
        const unsigned s0 = pref[k], s1 = pref[k + 1];
        for (unsigned i = s0 + threadIdx.x; i < s1; i += BLOCK) {
            const uint2 rec = scratch2[i];
            const unsigned col = rec.x & 0xFFFFFu;
            const unsigned lr  = rec.x >> 20;
            const float v = __uint_as_float(rec.y);
            const float4* f = (const float4*)(field + (size_t)col * NCOLS);
            const float4 f0 = f[0], f1 = f[1];
            atomicAdd(&acc[0 * RPB + lr], v * f0.x);
            atomicAdd(&acc[1 * RPB + lr], v * f0.y);
            atomicAdd(&acc[2 * RPB + lr], v * f0.z);
            atomicAdd(&acc[3 * RPB + lr], v * f0.w);
            atomicAdd(&acc[4 * RPB + lr], v * f1.x);
            atomicAdd(&acc[5 * RPB + lr], v * f1.y);
            atomicAdd(&acc[6 * RPB + lr], v * f1.z);
            atomicAdd(&acc[7 * RPB + lr], v * f1.w);
        }
    }
    __syncthreads();

    // Phase D: coalesced store (each row written exactly once -> no pre-zero of out)
    const size_t row0 = (size_t)b * RPB;
    for (int t = threadIdx.x; t < NCOLS * RPB; t += BLOCK) {
        int r = t >> 3, j = t & 7;
        size_t gr = row0 + (size_t)r;
        if (gr < (size_t)n) out[gr * NCOLS + j] = acc[j * RPB + r];
    }
}

// ---------- tier-2 accum: unsorted (no scratch2 space) ----------
__global__ __launch_bounds__(BLOCK) void k_accum1(
    const uint2* __restrict__ records, const unsigned* __restrict__ base,
    const float* __restrict__ field, float* __restrict__ out, int n)
{
    __shared__ float acc[NCOLS * RPB];
    for (int i = threadIdx.x; i < NCOLS * RPB; i += BLOCK) acc[i] = 0.f;
    __syncthreads();
    const int b = blockIdx.x;
    const unsigned beg = base[b], end = base[b + 1];
    for (unsigned i = beg + threadIdx.x; i < end; i += BLOCK) {
        const uint2 rec = records[i];
        const unsigned col = rec.x & 0xFFFFFu;
        const unsigned lr  = rec.x >> 20;
        const float v = __uint_as_float(rec.y);
        const float4* f = (const float4*)(field + (size_t)col * NCOLS);
        const float4 f0 = f[0], f1 = f[1];
        atomicAdd(&acc[0 * RPB + lr], v * f0.x);
        atomicAdd(&acc[1 * RPB + lr], v * f0.y);
        atomicAdd(&acc[2 * RPB + lr], v * f0.z);
        atomicAdd(&acc[3 * RPB + lr], v * f0.w);
        atomicAdd(&acc[4 * RPB + lr], v * f1.x);
        atomicAdd(&acc[5 * RPB + lr], v * f1.y);
        atomicAdd(&acc[6 * RPB + lr], v * f1.z);
        atomicAdd(&acc[7 * RPB + lr], v * f1.w);
    }
    __syncthreads();
    const size_t row0 = (size_t)b * RPB;
    for (int t = threadIdx.x; t < NCOLS * RPB; t += BLOCK) {
        int r = t >> 3, j = t & 7;
        size_t gr = row0 + (size_t)r;
        if (gr < (size_t)n) out[gr * NCOLS + j] = acc[j * RPB + r];
    }
}

// ---------- tier-3 fallback: direct atomic scatter ----------
__global__ __launch_bounds__(BLOCK) void lap_zero_kernel(float4* __restrict__ out, int n4) {
    int i = blockIdx.x * BLOCK + threadIdx.x;
    if (i < n4) out[i] = make_float4(0.f, 0.f, 0.f, 0.f);
}

__global__ __launch_bounds__(BLOCK) void lap_spmm_atomic(
    const float* __restrict__ vals, const void* __restrict__ rowp,
    const void* __restrict__ colp, const float* __restrict__ field,
    float* __restrict__ out, int nnz)
{
    const int is64 = detect_is64(rowp);
    int i = blockIdx.x * BLOCK + threadIdx.x;
    if (i >= nnz) return;
    float v = vals[i];
    int r = load_idx(rowp, i, is64);
    int c = load_idx(colp, i, is64);
    const float4* f = (const float4*)(field + (size_t)c * NCOLS);
    float4 f0 = f[0], f1 = f[1];
    float* o = out + (size_t)r * NCOLS;
    unsafeAtomicAdd(o + 0, v * f0.x);
    unsafeAtomicAdd(o + 1, v * f0.y);
    unsafeAtomicAdd(o + 2, v * f0.z);
    unsafeAtomicAdd(o + 3, v * f0.w);
    unsafeAtomicAdd(o + 4, v * f1.x);
    unsafeAtomicAdd(o + 5, v * f1.y);
    unsafeAtomicAdd(o + 6, v * f1.z);
    unsafeAtomicAdd(o + 7, v * f1.w);
}

extern "C" void kernel_launch(void* const* d_in, const int* in_sizes, int n_in,
                              void* d_out, int out_size, void* d_ws, size_t ws_size,
                              hipStream_t stream) {
    const float* field = (const float*)d_in[0];
    const float* vals  = (const float*)d_in[1];
    const void*  rowp  = d_in[2];
    const void*  colp  = d_in[3];
    float* out = (float*)d_out;

    const int nnz = in_sizes[1];
    const int n   = out_size / NCOLS;
    char* ws = (char*)d_ws;

    // ws layout
    const size_t o_hist  = 0;                                   // NB*NBKT u32 = 1 MB
    const size_t o_total = o_hist + (size_t)NB * NBKT * 4;      // NBKT u32
    const size_t o_base  = o_total + (size_t)NBKT * 4;          // NBKT+1 u32
    const size_t o_rec   = (o_base + (size_t)(NBKT + 1) * 4 + 255) & ~(size_t)255;
    const size_t o_scr2  = o_rec + (size_t)nnz * 8;
    const size_t need1   = o_scr2 + (size_t)nnz * 8;            // tier 1
    const size_t need2   = o_scr2;                              // tier 2

    if (n <= NBKT * RPB && n <= (1 << 20) && ws_size >= need2) {
        unsigned* hist  = (unsigned*)(ws + o_hist);
        unsigned* total = (unsigned*)(ws + o_total);
        unsigned* base  = (unsigned*)(ws + o_base);
        uint2*    rec   = (uint2*)(ws + o_rec);
        uint2*    scr2  = (uint2*)(ws + o_scr2);

        const int chunk = (nnz + NB - 1) / NB;

        k_hist<<<NB, BLOCK, 0, stream>>>(rowp, nnz, chunk, hist);
        k_colsum<<<(NBKT + BLOCK - 1) / BLOCK, BLOCK, 0, stream>>>(hist, total);
        k_scan<<<1, NBKT, 0, stream>>>(total, base);
        k_scatter<<<NB, BLOCK, 0, stream>>>(vals, rowp, colp, nnz, chunk, hist, base, rec);

        if (ws_size >= need1) {
            // col-window size: ceil_log2(n) - 5, clamped >= 0
            int lg = 0;
            while ((1u << lg) < (unsigned)n) ++lg;
            int lg2cpb = lg > 5 ? lg - 5 : 0;
            k_accum2<<<NBKT, BLOCK, 0, stream>>>(rec, base, scr2, field, out, n, lg2cpb);
        } else {
            k_accum1<<<NBKT, BLOCK, 0, stream>>>(rec, base, field, out, n);
        }
        return;
    }

    // tier-3 fallback
    const int n4 = out_size / 4;
    lap_zero_kernel<<<(n4 + BLOCK - 1) / BLOCK, BLOCK, 0, stream>>>((float4*)out, n4);
    lap_spmm_atomic<<<(nnz + BLOCK - 1) / BLOCK, BLOCK, 0, stream>>>(
        vals, rowp, colp, field, out, nnz);
}

// Round 5
// 1359.674 us; speedup vs baseline: 1.0392x; 1.0104x over previous
//
#include <hip/hip_runtime.h>

#define NCOLS  8
#define BLOCK  256
#define NB     512          // streaming blocks for hist/scatter
#define NBKT   1024         // row buckets (one accum block each)
#define LG2RPB 10
#define RPB    1024         // rows per bucket
#define NCB    32           // col windows per bucket
#define NCHUNK 16           // chunks for the transpose-scan
#define CB     (NB / NCHUNK)
#define CAP    23040        // max records/bucket for LDS u16 index sort (46 KB)

// ---------- index-width autodetect (int32 vs int64 COO indices) ----------
// All index values < 2^20, so int64 data has zero high words. P(false pos) ~ 1e-96.
__device__ __forceinline__ int detect_is64(const void* p) {
    const unsigned* w = (const unsigned*)p;
    int is64 = 1;
    #pragma unroll
    for (int k = 0; k < 16; ++k) is64 &= (w[2 * k + 1] == 0u) ? 1 : 0;
    return is64;
}

__device__ __forceinline__ int load_idx(const void* p, int i, int is64) {
    return is64 ? (int)((const long long*)p)[i] : ((const int*)p)[i];
}

// ---------- k1: per-block row-bucket histogram ----------
__global__ __launch_bounds__(BLOCK) void k_hist(
    const void* __restrict__ rowp, int nnz, int chunk, unsigned* __restrict__ hist)
{
    __shared__ unsigned h[NBKT];
    const int is64 = detect_is64(rowp);
    for (int i = threadIdx.x; i < NBKT; i += BLOCK) h[i] = 0u;
    __syncthreads();
    const int beg = blockIdx.x * chunk;
    const int end = min(nnz, beg + chunk);
    for (int i = beg + threadIdx.x; i < end; i += BLOCK)
        atomicAdd(&h[load_idx(rowp, i, is64) >> LG2RPB], 1u);
    __syncthreads();
    unsigned* row = hist + (size_t)blockIdx.x * NBKT;
    for (int i = threadIdx.x; i < NBKT; i += BLOCK) row[i] = h[i];
}

// ---------- k2a: partial sums per (chunk, bucket)  [16K threads, coalesced] ----------
__global__ __launch_bounds__(BLOCK) void k_partial(
    const unsigned* __restrict__ hist, unsigned* __restrict__ partial)
{
    const int t = blockIdx.x * BLOCK + threadIdx.x;     // t in [0, NCHUNK*NBKT)
    const int c = t >> 10, k = t & (NBKT - 1);
    unsigned s = 0;
    #pragma unroll 4
    for (int j = 0; j < CB; ++j) s += hist[(size_t)(c * CB + j) * NBKT + k];
    partial[(size_t)c * NBKT + k] = s;
}

// ---------- k2b: bucket totals + global scan + chunk bases  [1 block] ----------
__global__ __launch_bounds__(NBKT) void k_scan(
    unsigned* __restrict__ partial, unsigned* __restrict__ base)
{
    __shared__ unsigned s[NBKT];
    const int k = threadIdx.x;
    unsigned tot = 0;
    #pragma unroll
    for (int c = 0; c < NCHUNK; ++c) tot += partial[(size_t)c * NBKT + k];
    s[k] = tot;
    __syncthreads();
    for (int off = 1; off < NBKT; off <<= 1) {
        unsigned v = (k >= off) ? s[k - off] : 0u;
        __syncthreads();
        s[k] += v;
        __syncthreads();
    }
    unsigned run = s[k] - tot;                          // exclusive prefix
    base[k] = run;
    if (k == NBKT - 1) base[NBKT] = s[k];
    #pragma unroll
    for (int c = 0; c < NCHUNK; ++c) {
        unsigned t = partial[(size_t)c * NBKT + k];
        partial[(size_t)c * NBKT + k] = run;            // -> chunk base
        run += t;
    }
}

// ---------- k2c: apply — per-block write bases  [16K threads, coalesced] ----------
__global__ __launch_bounds__(BLOCK) void k_apply(
    unsigned* __restrict__ hist, const unsigned* __restrict__ partial)
{
    const int t = blockIdx.x * BLOCK + threadIdx.x;
    const int c = t >> 10, k = t & (NBKT - 1);
    unsigned run = partial[(size_t)c * NBKT + k];
    #pragma unroll 4
    for (int j = 0; j < CB; ++j) {
        const size_t idx = (size_t)(c * CB + j) * NBKT + k;
        unsigned v = hist[idx];
        hist[idx] = run;                                 // global write base
        run += v;
    }
}

// ---------- k3: scatter into bucket-grouped order (LDS cursors) ----------
// record = (localrow<<20 | col, bits(val)), 8 bytes
__global__ __launch_bounds__(BLOCK) void k_scatter(
    const float* __restrict__ vals, const void* __restrict__ rowp,
    const void* __restrict__ colp, int nnz, int chunk,
    const unsigned* __restrict__ hist, uint2* __restrict__ records)
{
    __shared__ unsigned cur[NBKT];
    const int is64 = detect_is64(rowp);
    const unsigned* wb = hist + (size_t)blockIdx.x * NBKT;
    for (int i = threadIdx.x; i < NBKT; i += BLOCK) cur[i] = wb[i];
    __syncthreads();
    const int beg = blockIdx.x * chunk;
    const int end = min(nnz, beg + chunk);
    for (int i = beg + threadIdx.x; i < end; i += BLOCK) {
        int r = load_idx(rowp, i, is64);
        int c = load_idx(colp, i, is64);
        float v = vals[i];
        unsigned pos = atomicAdd(&cur[r >> LG2RPB], 1u);
        records[pos] = make_uint2((((unsigned)r & (RPB - 1u)) << 20) | (unsigned)c,
                                  __float_as_uint(v));
    }
}

// ---------- k4: per-bucket LDS u16-index col-window sort + phased gather ----------
__global__ __launch_bounds__(BLOCK) void k_accum3(
    const uint2* __restrict__ records, const unsigned* __restrict__ base,
    const float* __restrict__ field, float* __restrict__ out, int n, int lg2cpb)
{
    __shared__ float acc[NCOLS * RPB];          // 32 KB, transposed acc[j*RPB+lr]
    __shared__ unsigned short sidx[CAP];        // 45 KB
    __shared__ unsigned cnt[NCB];
    __shared__ unsigned cur[NCB];

    const int b = blockIdx.x;
    const unsigned beg = base[b], end = base[b + 1];
    const unsigned m = end - beg;

    for (int i = threadIdx.x; i < NCOLS * RPB; i += BLOCK) acc[i] = 0.f;
    if (threadIdx.x < NCB) cnt[threadIdx.x] = 0u;
    __syncthreads();

    if (m <= CAP) {
        // pass 1: count col-windows (records segment -> L2)
        for (unsigned i = threadIdx.x; i < m; i += BLOCK) {
            unsigned cb = (records[beg + i].x & 0xFFFFFu) >> lg2cpb;
            atomicAdd(&cnt[cb], 1u);
        }
        __syncthreads();
        if (threadIdx.x == 0) {
            unsigned run = 0;
            #pragma unroll
            for (int k = 0; k < NCB; ++k) { cur[k] = run; run += cnt[k]; }
        }
        __syncthreads();
        // pass 2: counting-sort local indices by window (u16, in LDS)
        for (unsigned i = threadIdx.x; i < m; i += BLOCK) {
            unsigned cb = (records[beg + i].x & 0xFFFFFu) >> lg2cpb;
            sidx[atomicAdd(&cur[cb], 1u)] = (unsigned short)i;
        }
        __syncthreads();
        // pass 3: window-ordered accumulate (field window L2-hot across blocks)
        for (unsigned i = threadIdx.x; i < m; i += BLOCK) {
            const uint2 rec = records[beg + sidx[i]];
            const unsigned col = rec.x & 0xFFFFFu;
            const unsigned lr  = rec.x >> 20;
            const float v = __uint_as_float(rec.y);
            const float4* f = (const float4*)(field + (size_t)col * NCOLS);
            const float4 f0 = f[0], f1 = f[1];
            atomicAdd(&acc[0 * RPB + lr], v * f0.x);
            atomicAdd(&acc[1 * RPB + lr], v * f0.y);
            atomicAdd(&acc[2 * RPB + lr], v * f0.z);
            atomicAdd(&acc[3 * RPB + lr], v * f0.w);
            atomicAdd(&acc[4 * RPB + lr], v * f1.x);
            atomicAdd(&acc[5 * RPB + lr], v * f1.y);
            atomicAdd(&acc[6 * RPB + lr], v * f1.z);
            atomicAdd(&acc[7 * RPB + lr], v * f1.w);
        }
    } else {
        // oversize bucket (skewed input): unsorted accumulate
        for (unsigned i = beg + threadIdx.x; i < end; i += BLOCK) {
            const uint2 rec = records[i];
            const unsigned col = rec.x & 0xFFFFFu;
            const unsigned lr  = rec.x >> 20;
            const float v = __uint_as_float(rec.y);
            const float4* f = (const float4*)(field + (size_t)col * NCOLS);
            const float4 f0 = f[0], f1 = f[1];
            atomicAdd(&acc[0 * RPB + lr], v * f0.x);
            atomicAdd(&acc[1 * RPB + lr], v * f0.y);
            atomicAdd(&acc[2 * RPB + lr], v * f0.z);
            atomicAdd(&acc[3 * RPB + lr], v * f0.w);
            atomicAdd(&acc[4 * RPB + lr], v * f1.x);
            atomicAdd(&acc[5 * RPB + lr], v * f1.y);
            atomicAdd(&acc[6 * RPB + lr], v * f1.z);
            atomicAdd(&acc[7 * RPB + lr], v * f1.w);
        }
    }
    __syncthreads();

    // coalesced store; every output row written exactly once
    const size_t row0 = (size_t)b * RPB;
    for (int t = threadIdx.x; t < NCOLS * RPB; t += BLOCK) {
        int r = t >> 3, j = t & 7;
        size_t gr = row0 + (size_t)r;
        if (gr < (size_t)n) out[gr * NCOLS + j] = acc[j * RPB + r];
    }
}

// ---------- fallback: direct atomic scatter ----------
__global__ __launch_bounds__(BLOCK) void lap_zero_kernel(float4* __restrict__ out, int n4) {
    int i = blockIdx.x * BLOCK + threadIdx.x;
    if (i < n4) out[i] = make_float4(0.f, 0.f, 0.f, 0.f);
}

__global__ __launch_bounds__(BLOCK) void lap_spmm_atomic(
    const float* __restrict__ vals, const void* __restrict__ rowp,
    const void* __restrict__ colp, const float* __restrict__ field,
    float* __restrict__ out, int nnz)
{
    const int is64 = detect_is64(rowp);
    int i = blockIdx.x * BLOCK + threadIdx.x;
    if (i >= nnz) return;
    float v = vals[i];
    int r = load_idx(rowp, i, is64);
    int c = load_idx(colp, i, is64);
    const float4* f = (const float4*)(field + (size_t)c * NCOLS);
    float4 f0 = f[0], f1 = f[1];
    float* o = out + (size_t)r * NCOLS;
    unsafeAtomicAdd(o + 0, v * f0.x);
    unsafeAtomicAdd(o + 1, v * f0.y);
    unsafeAtomicAdd(o + 2, v * f0.z);
    unsafeAtomicAdd(o + 3, v * f0.w);
    unsafeAtomicAdd(o + 4, v * f1.x);
    unsafeAtomicAdd(o + 5, v * f1.y);
    unsafeAtomicAdd(o + 6, v * f1.z);
    unsafeAtomicAdd(o + 7, v * f1.w);
}

extern "C" void kernel_launch(void* const* d_in, const int* in_sizes, int n_in,
                              void* d_out, int out_size, void* d_ws, size_t ws_size,
                              hipStream_t stream) {
    const float* field = (const float*)d_in[0];
    const float* vals  = (const float*)d_in[1];
    const void*  rowp  = d_in[2];
    const void*  colp  = d_in[3];
    float* out = (float*)d_out;

    const int nnz = in_sizes[1];
    const int n   = out_size / NCOLS;
    char* ws = (char*)d_ws;

    // ws layout
    const size_t o_hist    = 0;                                     // NB*NBKT u32 = 2 MB
    const size_t o_partial = o_hist + (size_t)NB * NBKT * 4;        // NCHUNK*NBKT u32
    const size_t o_base    = o_partial + (size_t)NCHUNK * NBKT * 4; // NBKT+1 u32
    const size_t o_rec     = (o_base + (size_t)(NBKT + 1) * 4 + 255) & ~(size_t)255;
    const size_t need      = o_rec + (size_t)nnz * 8;

    if (n <= NBKT * RPB && n <= (1 << 20) && ws_size >= need) {
        unsigned* hist    = (unsigned*)(ws + o_hist);
        unsigned* partial = (unsigned*)(ws + o_partial);
        unsigned* base    = (unsigned*)(ws + o_base);
        uint2*    rec     = (uint2*)(ws + o_rec);

        const int chunk = (nnz + NB - 1) / NB;

        // col-window size: ceil_log2(n) - 5 (=> <= 32 windows)
        int lg = 0;
        while ((1u << lg) < (unsigned)n) ++lg;
        const int lg2cpb = lg > 5 ? lg - 5 : 0;

        k_hist<<<NB, BLOCK, 0, stream>>>(rowp, nnz, chunk, hist);
        k_partial<<<NCHUNK * NBKT / BLOCK, BLOCK, 0, stream>>>(hist, partial);
        k_scan<<<1, NBKT, 0, stream>>>(partial, base);
        k_apply<<<NCHUNK * NBKT / BLOCK, BLOCK, 0, stream>>>(hist, partial);
        k_scatter<<<NB, BLOCK, 0, stream>>>(vals, rowp, colp, nnz, chunk, hist, rec);
        k_accum3<<<NBKT, BLOCK, 0, stream>>>(rec, base, field, out, n, lg2cpb);
        return;
    }

    // fallback
    const int n4 = out_size / 4;
    lap_zero_kernel<<<(n4 + BLOCK - 1) / BLOCK, BLOCK, 0, stream>>>((float4*)out, n4);
    lap_spmm_atomic<<<(nnz + BLOCK - 1) / BLOCK, BLOCK, 0, stream>>>(
        vals, rowp, colp, field, out, nnz);
}